// Round 14
// baseline (840.784 us; speedup 1.0000x reference)
//
#include <hip/hip_runtime.h>

#define NROWS  32768
#define KCODES 1024
#define DDIM   512
#define LEVELS 4

#define CLOSS_OFF (NROWS * DDIM)
#define CODES_OFF (CLOSS_OFF + 1)
#define USAGE_OFF (CODES_OFF + NROWS * LEVELS)

typedef __attribute__((ext_vector_type(8))) short bf16x8;
typedef __attribute__((ext_vector_type(4))) float f32x4;
typedef __attribute__((ext_vector_type(8))) unsigned short u16x8;

__device__ __forceinline__ unsigned short bf16_rn(float f) {
  unsigned int u = __float_as_uint(f);
  return (unsigned short)((u + 0x7FFFu + ((u >> 16) & 1u)) >> 16);
}
__device__ __forceinline__ float bf16_f(unsigned short h) {
  return __uint_as_float(((unsigned int)h) << 16);
}
__device__ __forceinline__ void gload16(const void* g, void* l) {
  __builtin_amdgcn_global_load_lds(
      (const __attribute__((address_space(1))) unsigned int*)g,
      (__attribute__((address_space(3))) unsigned int*)l, 16, 0, 0);
}

// ---------------------------------------------------------------------------
// Fused: numpy-pairwise-tree row sum-of-squares (bit-exact, validated) +
// hi/lo bf16 split.  Splits stored with per-row 16B-chunk XOR swizzle
// (chunk' = chunk ^ (row&7)) so linear global_load_lds staging + XOR'd
// ds_read is bank-conflict-free (verified r8/r12: SQ_LDS_BANK_CONFLICT = 0).
// ---------------------------------------------------------------------------
__global__ __launch_bounds__(256) void prep_kernel(const float* __restrict__ in,
                                                   float* __restrict__ Rout,
                                                   unsigned short* __restrict__ hi,
                                                   unsigned short* __restrict__ lo,
                                                   int nrows) {
  __shared__ float buf[4][DDIM];
  const int wid  = threadIdx.x >> 6;
  const int lane = threadIdx.x & 63;
  const int row  = blockIdx.x * 4 + wid;
  if (row >= nrows) return;
  const float4* src = reinterpret_cast<const float4*>(in + (size_t)row * DDIM);
  float vals[8];
#pragma unroll
  for (int t = 0; t < 2; ++t) {
    const float4 v = src[lane * 2 + t];
    *reinterpret_cast<float4*>(&buf[wid][lane * 8 + t * 4]) = v;
    vals[t * 4 + 0] = v.x; vals[t * 4 + 1] = v.y;
    vals[t * 4 + 2] = v.z; vals[t * 4 + 3] = v.w;
  }
  u16x8 hh, ll;
#pragma unroll
  for (int e = 0; e < 8; ++e) {
    const unsigned short h = bf16_rn(vals[e]);
    hh[e] = h;
    ll[e] = bf16_rn(__fsub_rn(vals[e], bf16_f(h)));
  }
  const int pos = (lane & 56) | ((lane & 7) ^ (row & 7));  // chunk swizzle
  *reinterpret_cast<u16x8*>(&hi[(size_t)row * DDIM + pos * 8]) = hh;
  *reinterpret_cast<u16x8*>(&lo[(size_t)row * DDIM + pos * 8]) = ll;
  float chain = 0.0f;
  if (lane < 32) {
    const int base = (lane >> 3) * 128 + (lane & 7);
    float a = buf[wid][base];
    chain = __fmul_rn(a, a);
#pragma unroll
    for (int t = 1; t < 16; ++t) {
      a = buf[wid][base + 8 * t];
      chain = __fadd_rn(chain, __fmul_rn(a, a));
    }
  }
  chain = __fadd_rn(chain, __shfl_xor(chain, 1));
  chain = __fadd_rn(chain, __shfl_xor(chain, 2));
  chain = __fadd_rn(chain, __shfl_xor(chain, 4));
  chain = __fadd_rn(chain, __shfl_xor(chain, 8));
  chain = __fadd_rn(chain, __shfl_xor(chain, 16));
  if (lane == 0) Rout[row] = chain;
}

// ---------------------------------------------------------------------------
// bf16 split-GEMM distance + per-row top-3 keys.
// 128x128 tile, 4 waves (2x2 of 64x64, 4x4 frags of 16x16x32), BK=64,
// 2-buffer LDS (68.6KB -> 2 blocks/CU co-resident).
// Per K-tile: {issue ALL 8 gload_lds for t+1 FIRST (full-tile lead vs ~900cy
// HBM latency; prior tile's barrier guarantees the target buffer is free)},
// then per kh: load ar[0..3], then per cf {1 br ds_read -> 4 MFMA} -- br dies
// per column, liveness ~20 frag VGPRs, NO intra-tile sched_barrier so the
// compiler's fine lgkmcnt interleaves next br read under current MFMAs
// (r12's per-kh sched_barrier(0) blocked this overlap).  One vmcnt(0)+barrier
// per tile.  24 K-tiles = 3*512 segments (AhiBhi, AhiBlo, AloBhi) ascending;
// each acc[rf][cf] chain still kh0-then-kh1 -> d~ bit-identical to r5-r12.
// Swizzled chunk reads: 0 bank conflicts.  Key: (bits(max(d,0)) & ~127) |
// local_code(7b); per-wave top-3 + wave-pair trip merge (validated epilogue).
// Grid 2048 = 256rg x 8cbk, XCD-aligned rg=(p>>6)*8+(p&7), cbk=(p>>3)&7.
// ---------------------------------------------------------------------------
__global__ __launch_bounds__(256, 2) void gemm_topk_kernel(
    const unsigned short* __restrict__ Ahi, const unsigned short* __restrict__ Alo,
    const unsigned short* __restrict__ Bhi, const unsigned short* __restrict__ Blo,
    const float* __restrict__ Rrow, const float* __restrict__ cbsq,
    unsigned int* __restrict__ keys) {
  __shared__ short ring[2][16384];            // per buf: A[128][64] @0, B[128][64] @8192
  __shared__ unsigned int trip[4][64][3];
  const int tid  = threadIdx.x;
  const int lane = tid & 63;
  const int wid  = tid >> 6;
  const int wm = wid >> 1, wn = wid & 1;      // wave tile: rows wm*64, cols wn*64
  const int c = lane & 15, q = lane >> 4;
  const int p = blockIdx.x;
  const int rg  = (p >> 6) * 8 + (p & 7);     // 0..255
  const int cbk = (p >> 3) & 7;               // 0..7
  const int rowBase = rg * 128;
  const int colBase = cbk * 128;

  f32x4 acc[4][4];
#pragma unroll
  for (int rf = 0; rf < 4; ++rf)
#pragma unroll
    for (int cf = 0; cf < 4; ++cf) acc[rf][cf] = (f32x4)0.0f;

  const int laneOff = (lane >> 3) * 1024 + (lane & 7) * 16;

  auto STAGE = [&](int t) {                   // 8 gload16/thread, all up front
    const char* Ab = ((t >> 3) == 2) ? (const char*)Alo : (const char*)Ahi;
    const char* Bb = ((t >> 3) == 1) ? (const char*)Blo : (const char*)Bhi;
    const int seg = (t & 7) * 128;
    short* dst = &ring[t & 1][0];
#pragma unroll
    for (int l = 0; l < 4; ++l) {
      const int g = wid + 4 * l;              // 0..15, 8 rows each
      gload16(Ab + (size_t)(rowBase + g * 8) * 1024 + seg + laneOff, dst + g * 512);
      gload16(Bb + (size_t)(colBase + g * 8) * 1024 + seg + laneOff, dst + 8192 + g * 512);
    }
  };

  STAGE(0);
  asm volatile("s_waitcnt vmcnt(0)" ::: "memory");
  __builtin_amdgcn_s_barrier();
  __builtin_amdgcn_sched_barrier(0);

  for (int t = 0; t < 24; ++t) {
    if (t + 1 < 24) STAGE(t + 1);             // full-tile lead; other buffer
    const short* As = &ring[t & 1][0];
    const short* Bs = &ring[t & 1][8192];
#pragma unroll
    for (int kh = 0; kh < 2; ++kh) {          // kh ascending: per-acc chain preserved
      const int ch = ((kh * 4 + q) ^ (c & 7)) * 8;   // deswizzled 16B chunk
      bf16x8 ar[4];
#pragma unroll
      for (int rf = 0; rf < 4; ++rf)
        ar[rf] = *reinterpret_cast<const bf16x8*>(&As[(wm * 64 + rf * 16 + c) * 64 + ch]);
      __builtin_amdgcn_s_setprio(1);
#pragma unroll
      for (int cf = 0; cf < 4; ++cf) {
        const bf16x8 br = *reinterpret_cast<const bf16x8*>(&Bs[(wn * 64 + cf * 16 + c) * 64 + ch]);
#pragma unroll
        for (int rf = 0; rf < 4; ++rf)
          acc[rf][cf] = __builtin_amdgcn_mfma_f32_16x16x32_bf16(ar[rf], br, acc[rf][cf], 0, 0, 0);
      }
      __builtin_amdgcn_s_setprio(0);
    }
    if (t + 1 < 24) {
      asm volatile("s_waitcnt vmcnt(0)" ::: "memory");
      __builtin_amdgcn_s_barrier();
      __builtin_amdgcn_sched_barrier(0);
    }
  }

  // epilogue inputs loaded here (not hoisted across the K-loop)
  float4 R4[4];
  float cq[4];
#pragma unroll
  for (int rf = 0; rf < 4; ++rf)
    R4[rf] = *reinterpret_cast<const float4*>(&Rrow[rowBase + wm * 64 + rf * 16 + q * 4]);
#pragma unroll
  for (int cf = 0; cf < 4; ++cf)
    cq[cf] = cbsq[colBase + wn * 64 + cf * 16 + c];

  // epilogue: d~ -> per-wave top-3 over 64 cols (validated math)
#pragma unroll
  for (int rf = 0; rf < 4; ++rf) {
#pragma unroll
    for (int jj = 0; jj < 4; ++jj) {
      const float Rv = (jj == 0) ? R4[rf].x : (jj == 1) ? R4[rf].y : (jj == 2) ? R4[rf].z : R4[rf].w;
      unsigned int v[4];
#pragma unroll
      for (int cf = 0; cf < 4; ++cf) {
        float d = __fadd_rn(__fsub_rn(Rv, __fmul_rn(2.0f, acc[rf][cf][jj])), cq[cf]);
        d = fmaxf(d, 0.0f);
        v[cf] = (__float_as_uint(d) & 0xFFFFFF80u) | (unsigned int)(wn * 64 + cf * 16 + c);
      }
      const unsigned int m01 = min(v[0], v[1]), M01 = max(v[0], v[1]);
      const unsigned int m23 = min(v[2], v[3]), M23 = max(v[2], v[3]);
      unsigned int s0 = min(m01, m23);
      const unsigned int x = max(m01, m23), mM = min(M01, M23);
      unsigned int s1 = min(x, mM);
      unsigned int s2 = min(max(x, mM), max(M01, M23));
#pragma unroll
      for (int m = 1; m < 16; m <<= 1) {
        const unsigned int t0 = (unsigned int)__shfl_xor((int)s0, m);
        const unsigned int t1 = (unsigned int)__shfl_xor((int)s1, m);
        const unsigned int t2 = (unsigned int)__shfl_xor((int)s2, m);
        const unsigned int bb = max(s0, t0), aa = min(s1, t1);
        const unsigned int r0 = min(s0, t0);
        const unsigned int r1 = min(bb, aa);
        const unsigned int r2 = min(max(bb, aa), min(s2, t2));
        s0 = r0; s1 = r1; s2 = r2;
      }
      if (c == 0) {
        const int lrow = rf * 16 + q * 4 + jj;      // 0..63 within wave
        trip[wid][lrow][0] = s0;
        trip[wid][lrow][1] = s1;
        trip[wid][lrow][2] = s2;
      }
    }
  }
  __syncthreads();
  // wave-pair merge (wn 0/1 share rows): even wid writes the 128-col triple
  if ((wid & 1) == 0) {
    const unsigned int a0 = trip[wid][lane][0], a1 = trip[wid][lane][1], a2 = trip[wid][lane][2];
    const unsigned int b0 = trip[wid + 1][lane][0], b1 = trip[wid + 1][lane][1], b2 = trip[wid + 1][lane][2];
    const unsigned int bb = max(a0, b0), aa = min(a1, b1);
    const unsigned int s0 = min(a0, b0);
    const unsigned int s1 = min(bb, aa);
    const unsigned int s2 = min(max(bb, aa), min(a2, b2));
    const int row = rowBase + (wid >> 1) * 64 + lane;
    unsigned int* kp = keys + (size_t)row * 24 + cbk * 3;
    kp[0] = s0; kp[1] = s1; kp[2] = s2;
  }
}

// ---------------------------------------------------------------------------
// Fused per-level finish: winner (reduce + exact guarded rescore, validated)
// -> codes, residual subtract (exact), next-level splits (SWIZZLED like prep),
// numpy-tree row norm, usage bincount.  One wave per row.
// do_write=0 at the last level skips the 64MB residual store (finalize_zq
// overwrites zq anyway); R/chain still computed for closs.
// ---------------------------------------------------------------------------
__global__ __launch_bounds__(256) void level_finish_kernel(
    const unsigned int* __restrict__ keys, const float* rin, float* rout,
    const float* __restrict__ cb, const float* __restrict__ cbsq,
    float* __restrict__ Rrow, float* __restrict__ usage,
    float* __restrict__ codes, unsigned short* __restrict__ Ahi,
    unsigned short* __restrict__ Alo, int level, int do_split, int do_write) {
  __shared__ float buf[4][DDIM];
  const int wid  = threadIdx.x >> 6;
  const int lane = threadIdx.x & 63;
  const int row  = blockIdx.x * 4 + wid;

  // ---- winner ----
  const unsigned int k = (lane < 24) ? keys[(size_t)row * 24 + lane] : 0xFFFFFFFFu;
  const int mycode = (lane < 24) ? ((lane / 3) * 128 + (int)(k & 127u)) : 0x7FFFFFFF;
  const float Rv_old = Rrow[row];
  unsigned int g = k;
#pragma unroll
  for (int m = 1; m < 64; m <<= 1) g = min(g, (unsigned int)__shfl_xor((int)g, m));
  const float dmin = __uint_as_float(g & 0xFFFFFF80u);
  const float W = 0.010f + 5.0e-4f * sqrtf(Rv_old);
  const bool cand = (lane < 24) && (__uint_as_float(k & 0xFFFFFF80u) <= dmin + W);
  const unsigned long long mask = __ballot(cand);
  int winner;
  if (__popcll(mask) == 1) {
    int w = cand ? mycode : 0x7FFFFFFF;
#pragma unroll
    for (int m = 1; m < 64; m <<= 1) w = min(w, __shfl_xor(w, m));
    winner = w;
  } else {
    float db = __builtin_inff();
    int   ib = 0x7FFFFFFF;
    if (cand) {
      const float4* rr = reinterpret_cast<const float4*>(rin + (size_t)row * DDIM);
      const float4* cc = reinterpret_cast<const float4*>(cb + (size_t)mycode * DDIM);
      float pp = 0.0f;
      for (int t = 0; t < DDIM / 4; ++t) {   // exact ascending fmaf chain (BLAS order)
        const float4 a = rr[t], b = cc[t];
        pp = fmaf(a.x, b.x, pp); pp = fmaf(a.y, b.y, pp);
        pp = fmaf(a.z, b.z, pp); pp = fmaf(a.w, b.w, pp);
      }
      db = __fadd_rn(__fsub_rn(Rv_old, __fmul_rn(2.0f, pp)), cbsq[mycode]);
      ib = mycode;
    }
#pragma unroll
    for (int m = 1; m < 64; m <<= 1) {
      const float od = __shfl_xor(db, m);
      const int   oi = __shfl_xor(ib, m);
      if (od < db || (od == db && oi < ib)) { db = od; ib = oi; }
    }
    winner = ib;
  }

  // ---- subtract + split + rowsq ----
  const float4* r4 = reinterpret_cast<const float4*>(rin + (size_t)row * DDIM) + lane * 2;
  const float4* q4 = reinterpret_cast<const float4*>(cb + (size_t)winner * DDIM) + lane * 2;
  float4* o4 = reinterpret_cast<float4*>(rout + (size_t)row * DDIM) + lane * 2;
  float vals[8];
#pragma unroll
  for (int t = 0; t < 2; ++t) {
    float4 r = r4[t], qv = q4[t], o;
    o.x = __fsub_rn(r.x, qv.x);
    o.y = __fsub_rn(r.y, qv.y);
    o.z = __fsub_rn(r.z, qv.z);
    o.w = __fsub_rn(r.w, qv.w);
    if (do_write) o4[t] = o;
    *reinterpret_cast<float4*>(&buf[wid][lane * 8 + t * 4]) = o;
    vals[t * 4 + 0] = o.x; vals[t * 4 + 1] = o.y;
    vals[t * 4 + 2] = o.z; vals[t * 4 + 3] = o.w;
  }
  if (do_split) {
    u16x8 hh, ll;
#pragma unroll
    for (int e = 0; e < 8; ++e) {
      const unsigned short h = bf16_rn(vals[e]);
      hh[e] = h;
      ll[e] = bf16_rn(__fsub_rn(vals[e], bf16_f(h)));
    }
    const int pos = (lane & 56) | ((lane & 7) ^ (row & 7));  // chunk swizzle (match prep)
    *reinterpret_cast<u16x8*>(&Ahi[(size_t)row * DDIM + pos * 8]) = hh;
    *reinterpret_cast<u16x8*>(&Alo[(size_t)row * DDIM + pos * 8]) = ll;
  }
  float chain = 0.0f;
  if (lane < 32) {
    const int base = (lane >> 3) * 128 + (lane & 7);
    float a = buf[wid][base];
    chain = __fmul_rn(a, a);
#pragma unroll
    for (int t = 1; t < 16; ++t) {
      a = buf[wid][base + 8 * t];
      chain = __fadd_rn(chain, __fmul_rn(a, a));
    }
  }
  chain = __fadd_rn(chain, __shfl_xor(chain, 1));
  chain = __fadd_rn(chain, __shfl_xor(chain, 2));
  chain = __fadd_rn(chain, __shfl_xor(chain, 4));
  chain = __fadd_rn(chain, __shfl_xor(chain, 8));
  chain = __fadd_rn(chain, __shfl_xor(chain, 16));
  if (lane == 0) {
    Rrow[row] = chain;
    atomicAdd(&usage[winner], 1.0f);
    codes[(size_t)row * LEVELS + level] = (float)winner;
  }
}

// ---------------------------------------------------------------------------
// Fallback VALU argmin (round-3 path, bit-exact-validated) for small ws.
// ---------------------------------------------------------------------------
#define BM 64
#define BN 256
#define DT 32
#define LDP (DT + 4)

__global__ __launch_bounds__(256) void argmin_kernel(const float* __restrict__ res,
                                                     const float* __restrict__ cb,
                                                     const float* __restrict__ Rr_,
                                                     const float* __restrict__ cbsq,
                                                     float* __restrict__ codes,
                                                     int level) {
  __shared__ float As_[BM][LDP];
  __shared__ float Bs_[BN][LDP];
  const int tid = threadIdx.x;
  const int tx = tid & 15;
  const int ty = tid >> 4;
  const size_t brow = (size_t)blockIdx.x * BM;
  float minv[4]; int mini[4]; float Rv[4];
#pragma unroll
  for (int i = 0; i < 4; ++i) { minv[i] = __builtin_inff(); mini[i] = 0; Rv[i] = Rr_[brow + ty + 16 * i]; }
  for (int nc = 0; nc < KCODES; nc += BN) {
    float acc[4][16];
#pragma unroll
    for (int i = 0; i < 4; ++i)
#pragma unroll
      for (int j = 0; j < 16; ++j) acc[i][j] = 0.0f;
    for (int dt = 0; dt < DDIM; dt += DT) {
      __syncthreads();
#pragma unroll
      for (int qq = 0; qq < 2; ++qq) {
        const int ff = tid + qq * 256; const int r = ff >> 3; const int seg = (ff & 7) * 4;
        *reinterpret_cast<float4*>(&As_[r][seg]) =
            *reinterpret_cast<const float4*>(&res[(brow + r) * DDIM + dt + seg]);
      }
#pragma unroll
      for (int qq = 0; qq < 8; ++qq) {
        const int ff = tid + qq * 256; const int r = ff >> 3; const int seg = (ff & 7) * 4;
        *reinterpret_cast<float4*>(&Bs_[r][seg]) =
            *reinterpret_cast<const float4*>(&cb[(size_t)(nc + r) * DDIM + dt + seg]);
      }
      __syncthreads();
#pragma unroll
      for (int dd = 0; dd < DT; dd += 4) {
        float4 av[4];
#pragma unroll
        for (int i = 0; i < 4; ++i) av[i] = *reinterpret_cast<const float4*>(&As_[ty + 16 * i][dd]);
#pragma unroll
        for (int j = 0; j < 16; ++j) {
          const float4 bv = *reinterpret_cast<const float4*>(&Bs_[tx + 16 * j][dd]);
#pragma unroll
          for (int i = 0; i < 4; ++i) {
            acc[i][j] = fmaf(av[i].x, bv.x, acc[i][j]);
            acc[i][j] = fmaf(av[i].y, bv.y, acc[i][j]);
            acc[i][j] = fmaf(av[i].z, bv.z, acc[i][j]);
            acc[i][j] = fmaf(av[i].w, bv.w, acc[i][j]);
          }
        }
      }
    }
#pragma unroll
    for (int j = 0; j < 16; ++j) {
      const int code = nc + tx + 16 * j;
      const float cq = cbsq[code];
#pragma unroll
      for (int i = 0; i < 4; ++i) {
        const float dist = __fadd_rn(__fsub_rn(Rv[i], __fmul_rn(2.0f, acc[i][j])), cq);
        if (dist < minv[i]) { minv[i] = dist; mini[i] = code; }
      }
    }
  }
#pragma unroll
  for (int m = 1; m < 16; m <<= 1) {
#pragma unroll
    for (int i = 0; i < 4; ++i) {
      const float ov = __shfl_xor(minv[i], m);
      const int   oi = __shfl_xor(mini[i], m);
      if (ov < minv[i] || (ov == minv[i] && oi < mini[i])) { minv[i] = ov; mini[i] = oi; }
    }
  }
  if (tx == 0) {
#pragma unroll
    for (int i = 0; i < 4; ++i)
      codes[(brow + ty + 16 * i) * LEVELS + level] = (float)mini[i];
  }
}

// fallback per-level tail (validated)
__global__ __launch_bounds__(256) void sub_split_rowsq_kernel(
    const float* rin, float* rout, const float* __restrict__ cb,
    const float* __restrict__ codes, float* __restrict__ usage,
    float* __restrict__ Rout, int level) {
  __shared__ float buf[4][DDIM];
  const int wid  = threadIdx.x >> 6;
  const int lane = threadIdx.x & 63;
  const int row  = blockIdx.x * 4 + wid;
  const int idx = (int)codes[(size_t)row * LEVELS + level];
  const float4* r4 = reinterpret_cast<const float4*>(rin + (size_t)row * DDIM) + lane * 2;
  const float4* q4 = reinterpret_cast<const float4*>(cb + (size_t)idx * DDIM) + lane * 2;
  float4* o4 = reinterpret_cast<float4*>(rout + (size_t)row * DDIM) + lane * 2;
#pragma unroll
  for (int t = 0; t < 2; ++t) {
    float4 r = r4[t], q = q4[t], o;
    o.x = __fsub_rn(r.x, q.x);
    o.y = __fsub_rn(r.y, q.y);
    o.z = __fsub_rn(r.z, q.z);
    o.w = __fsub_rn(r.w, q.w);
    o4[t] = o;
    *reinterpret_cast<float4*>(&buf[wid][lane * 8 + t * 4]) = o;
  }
  float chain = 0.0f;
  if (lane < 32) {
    const int base = (lane >> 3) * 128 + (lane & 7);
    float a = buf[wid][base];
    chain = __fmul_rn(a, a);
#pragma unroll
    for (int t = 1; t < 16; ++t) {
      a = buf[wid][base + 8 * t];
      chain = __fadd_rn(chain, __fmul_rn(a, a));
    }
  }
  chain = __fadd_rn(chain, __shfl_xor(chain, 1));
  chain = __fadd_rn(chain, __shfl_xor(chain, 2));
  chain = __fadd_rn(chain, __shfl_xor(chain, 4));
  chain = __fadd_rn(chain, __shfl_xor(chain, 8));
  chain = __fadd_rn(chain, __shfl_xor(chain, 16));
  if (lane == 0) {
    Rout[row] = chain;
    atomicAdd(&usage[idx], 1.0f);
  }
}

__global__ __launch_bounds__(256) void sumR_kernel(const float* __restrict__ R,
                                                   float* __restrict__ slot) {
  const int t = blockIdx.x * 256 + threadIdx.x;
  float s = 0.0f;
#pragma unroll
  for (int k = 0; k < 4; ++k) s += R[t + k * 8192];
#pragma unroll
  for (int m = 1; m < 64; m <<= 1) s += __shfl_xor(s, m);
  __shared__ float ws[4];
  if ((threadIdx.x & 63) == 0) ws[threadIdx.x >> 6] = s;
  __syncthreads();
  if (threadIdx.x == 0) atomicAdd(slot, ((ws[0] + ws[1]) + (ws[2] + ws[3])));
}

__global__ __launch_bounds__(256) void finalize_zq_kernel(const float* __restrict__ z,
                                                          const float* __restrict__ cb,
                                                          const float* __restrict__ codes,
                                                          float* __restrict__ zq) {
  const int row  = (int)((blockIdx.x * 256 + threadIdx.x) >> 6);
  const int lane = threadIdx.x & 63;
  int c[4];
#pragma unroll
  for (int l = 0; l < 4; ++l) c[l] = (int)codes[(size_t)row * LEVELS + l];
#pragma unroll
  for (int t = 0; t < 2; ++t) {
    const int o = lane * 8 + t * 4;
    float4 s = *reinterpret_cast<const float4*>(&cb[(size_t)c[0] * DDIM + o]);
#pragma unroll
    for (int l = 1; l < 4; ++l) {
      const float4 q = *reinterpret_cast<const float4*>(&cb[(size_t)c[l] * DDIM + o]);
      s.x = __fadd_rn(s.x, q.x);
      s.y = __fadd_rn(s.y, q.y);
      s.z = __fadd_rn(s.z, q.z);
      s.w = __fadd_rn(s.w, q.w);
    }
    const float4 zz = *reinterpret_cast<const float4*>(&z[(size_t)row * DDIM + o]);
    float4 r;
    r.x = __fadd_rn(zz.x, __fsub_rn(s.x, zz.x));
    r.y = __fadd_rn(zz.y, __fsub_rn(s.y, zz.y));
    r.z = __fadd_rn(zz.z, __fsub_rn(s.z, zz.z));
    r.w = __fadd_rn(zz.w, __fsub_rn(s.w, zz.w));
    *reinterpret_cast<float4*>(&zq[(size_t)row * DDIM + o]) = r;
  }
}

__global__ void closs_final_kernel(const float* __restrict__ acc, float* __restrict__ out) {
  if (threadIdx.x == 0 && blockIdx.x == 0) {
    float c = 0.0f;
#pragma unroll
    for (int l = 0; l < 4; ++l)
      c = __fadd_rn(c, __fmul_rn(acc[l], 0x1p-24f));
    out[0] = c;
  }
}

extern "C" void kernel_launch(void* const* d_in, const int* in_sizes, int n_in,
                              void* d_out, int out_size, void* d_ws, size_t ws_size,
                              hipStream_t stream) {
  const float* z  = (const float*)d_in[0];
  const float* cb = (const float*)d_in[1];
  float* out   = (float*)d_out;
  float* zq    = out;
  float* closs = out + CLOSS_OFF;
  float* codes = out + CODES_OFF;
  float* usage = out + USAGE_OFF;

  float* R    = (float*)d_ws;
  float* cbsq = R + NROWS;
  float* cacc = cbsq + KCODES;

  const size_t WS_NEED = (size_t)(NROWS + KCODES + 4) * 4       // R, cbsq, cacc
                       + (size_t)NROWS * 24 * 4                  // keys
                       + 2ull * KCODES * DDIM * 2                // B splits
                       + 2ull * NROWS * DDIM * 2;                // A splits

  hipMemsetAsync(usage, 0, KCODES * sizeof(float), stream);
  hipMemsetAsync(cacc, 0, LEVELS * sizeof(float), stream);

  if (ws_size >= WS_NEED) {
    unsigned int*   keys = (unsigned int*)(cacc + 4);
    unsigned short* Bhi  = (unsigned short*)(keys + (size_t)NROWS * 24);
    unsigned short* Blo  = Bhi + (size_t)KCODES * DDIM;
    unsigned short* Ahi  = Blo + (size_t)KCODES * DDIM;
    unsigned short* Alo  = Ahi + (size_t)NROWS * DDIM;

    prep_kernel<<<NROWS / 4, 256, 0, stream>>>(z, R, Ahi, Alo, NROWS);
    prep_kernel<<<KCODES / 4, 256, 0, stream>>>(cb, cbsq, Bhi, Blo, KCODES);

    for (int l = 0; l < LEVELS; ++l) {
      const float* res = (l == 0) ? z : zq;
      gemm_topk_kernel<<<2048, 256, 0, stream>>>(Ahi, Alo, Bhi, Blo, R, cbsq, keys);
      level_finish_kernel<<<NROWS / 4, 256, 0, stream>>>(keys, res, zq, cb, cbsq, R,
                                                         usage, codes, Ahi, Alo, l,
                                                         (l < 3) ? 1 : 0,
                                                         (l < 3) ? 1 : 0);
      sumR_kernel<<<32, 256, 0, stream>>>(R, cacc + l);
    }
  } else {
    prep_kernel<<<NROWS / 4, 256, 0, stream>>>(z, R, (unsigned short*)(cacc + 4),
                                               (unsigned short*)(cacc + 4) + NROWS, NROWS);
    prep_kernel<<<KCODES / 4, 256, 0, stream>>>(cb, cbsq, (unsigned short*)(cacc + 4),
                                                (unsigned short*)(cacc + 4) + KCODES, KCODES);
    for (int l = 0; l < LEVELS; ++l) {
      const float* res = (l == 0) ? z : zq;
      argmin_kernel<<<NROWS / BM, 256, 0, stream>>>(res, cb, R, cbsq, codes, l);
      sub_split_rowsq_kernel<<<NROWS / 4, 256, 0, stream>>>(res, zq, cb, codes, usage, R, l);
      sumR_kernel<<<32, 256, 0, stream>>>(R, cacc + l);
    }
  }

  finalize_zq_kernel<<<NROWS / 4, 256, 0, stream>>>(z, cb, codes, zq);
  closs_final_kernel<<<1, 64, 0, stream>>>(cacc, closs);
}

// Round 15
// 798.290 us; speedup vs baseline: 1.0532x; 1.0532x over previous
//
#include <hip/hip_runtime.h>

#define NROWS  32768
#define KCODES 1024
#define DDIM   512
#define LEVELS 4

#define CLOSS_OFF (NROWS * DDIM)
#define CODES_OFF (CLOSS_OFF + 1)
#define USAGE_OFF (CODES_OFF + NROWS * LEVELS)

typedef __attribute__((ext_vector_type(8))) short bf16x8;
typedef __attribute__((ext_vector_type(4))) float f32x4;
typedef __attribute__((ext_vector_type(8))) unsigned short u16x8;

__device__ __forceinline__ unsigned short bf16_rn(float f) {
  unsigned int u = __float_as_uint(f);
  return (unsigned short)((u + 0x7FFFu + ((u >> 16) & 1u)) >> 16);
}
__device__ __forceinline__ float bf16_f(unsigned short h) {
  return __uint_as_float(((unsigned int)h) << 16);
}
__device__ __forceinline__ void gload16(const void* g, void* l) {
  __builtin_amdgcn_global_load_lds(
      (const __attribute__((address_space(1))) unsigned int*)g,
      (__attribute__((address_space(3))) unsigned int*)l, 16, 0, 0);
}

// ---------------------------------------------------------------------------
// Fused: numpy-pairwise-tree row sum-of-squares (bit-exact, validated) +
// hi/lo bf16 split.  Splits stored with per-row 16B-chunk XOR swizzle
// (chunk' = chunk ^ (row&7)) so linear global_load_lds staging + XOR'd
// ds_read is bank-conflict-free (verified r8/r12: SQ_LDS_BANK_CONFLICT = 0).
// ---------------------------------------------------------------------------
__global__ __launch_bounds__(256) void prep_kernel(const float* __restrict__ in,
                                                   float* __restrict__ Rout,
                                                   unsigned short* __restrict__ hi,
                                                   unsigned short* __restrict__ lo,
                                                   int nrows) {
  __shared__ float buf[4][DDIM];
  const int wid  = threadIdx.x >> 6;
  const int lane = threadIdx.x & 63;
  const int row  = blockIdx.x * 4 + wid;
  if (row >= nrows) return;
  const float4* src = reinterpret_cast<const float4*>(in + (size_t)row * DDIM);
  float vals[8];
#pragma unroll
  for (int t = 0; t < 2; ++t) {
    const float4 v = src[lane * 2 + t];
    *reinterpret_cast<float4*>(&buf[wid][lane * 8 + t * 4]) = v;
    vals[t * 4 + 0] = v.x; vals[t * 4 + 1] = v.y;
    vals[t * 4 + 2] = v.z; vals[t * 4 + 3] = v.w;
  }
  u16x8 hh, ll;
#pragma unroll
  for (int e = 0; e < 8; ++e) {
    const unsigned short h = bf16_rn(vals[e]);
    hh[e] = h;
    ll[e] = bf16_rn(__fsub_rn(vals[e], bf16_f(h)));
  }
  const int pos = (lane & 56) | ((lane & 7) ^ (row & 7));  // chunk swizzle
  *reinterpret_cast<u16x8*>(&hi[(size_t)row * DDIM + pos * 8]) = hh;
  *reinterpret_cast<u16x8*>(&lo[(size_t)row * DDIM + pos * 8]) = ll;
  float chain = 0.0f;
  if (lane < 32) {
    const int base = (lane >> 3) * 128 + (lane & 7);
    float a = buf[wid][base];
    chain = __fmul_rn(a, a);
#pragma unroll
    for (int t = 1; t < 16; ++t) {
      a = buf[wid][base + 8 * t];
      chain = __fadd_rn(chain, __fmul_rn(a, a));
    }
  }
  chain = __fadd_rn(chain, __shfl_xor(chain, 1));
  chain = __fadd_rn(chain, __shfl_xor(chain, 2));
  chain = __fadd_rn(chain, __shfl_xor(chain, 4));
  chain = __fadd_rn(chain, __shfl_xor(chain, 8));
  chain = __fadd_rn(chain, __shfl_xor(chain, 16));
  if (lane == 0) Rout[row] = chain;
}

// ---------------------------------------------------------------------------
// bf16 split-GEMM distance + per-row top-3 keys.  (r12 configuration — best
// measured: 147us/dispatch, 0 spill, 0 bank conflicts.)
// 128x128 tile, 4 waves (2x2 of 64x64, 4x4 frags of 16x16x32), BK=64,
// 2-buffer LDS (68.6KB -> 2 blocks/CU co-resident to cover drains).
// Per K-tile, TWO sub-phases (kh=0,1), each: {8 ds_read -> 4 gload_lds of
// tile t+1 -> 16 MFMA in setprio -> sched_barrier(0)}; one vmcnt(0)+barrier
// per tile.  The sched_barrier(0) per sub-phase is the no-spill property
// (without it the scheduler interleaves both kh bodies -> scratch spill).
// 24 K-tiles = 3*512 segments (AhiBhi, AhiBlo, AloBhi) ascending -> d~
// bit-identical to r5-r12.  Swizzled chunk reads: 0 bank conflicts.
// Key: (bits(max(d,0)) & ~127) | local_code(7b); per-wave top-3 + wave-pair
// trip merge (validated epilogue).  Grid 2048 = 256rg x 8cbk, XCD-aligned
// mapping rg=(p>>6)*8+(p&7), cbk=(p>>3)&7 (r7-proven minimal FETCH).
// Schedule families measured clean: r8 counted-vmcnt=153, r12 this=147,
// r14 stage-first=156 -> this is the structure's empirical floor.
// ---------------------------------------------------------------------------
__global__ __launch_bounds__(256, 2) void gemm_topk_kernel(
    const unsigned short* __restrict__ Ahi, const unsigned short* __restrict__ Alo,
    const unsigned short* __restrict__ Bhi, const unsigned short* __restrict__ Blo,
    const float* __restrict__ Rrow, const float* __restrict__ cbsq,
    unsigned int* __restrict__ keys) {
  __shared__ short ring[2][16384];            // per buf: A[128][64] @0, B[128][64] @8192
  __shared__ unsigned int trip[4][64][3];
  const int tid  = threadIdx.x;
  const int lane = tid & 63;
  const int wid  = tid >> 6;
  const int wm = wid >> 1, wn = wid & 1;      // wave tile: rows wm*64, cols wn*64
  const int c = lane & 15, q = lane >> 4;
  const int p = blockIdx.x;
  const int rg  = (p >> 6) * 8 + (p & 7);     // 0..255
  const int cbk = (p >> 3) & 7;               // 0..7
  const int rowBase = rg * 128;
  const int colBase = cbk * 128;

  f32x4 acc[4][4];
#pragma unroll
  for (int rf = 0; rf < 4; ++rf)
#pragma unroll
    for (int cf = 0; cf < 4; ++cf) acc[rf][cf] = (f32x4)0.0f;

  const int laneOff = (lane >> 3) * 1024 + (lane & 7) * 16;

  auto STAGE_half = [&](int t, int h) {       // 4 gload16/thread per half
    const char* Ab = ((t >> 3) == 2) ? (const char*)Alo : (const char*)Ahi;
    const char* Bb = ((t >> 3) == 1) ? (const char*)Blo : (const char*)Bhi;
    const int seg = (t & 7) * 128;
    short* dst = &ring[t & 1][0];
#pragma unroll
    for (int l = h * 2; l < h * 2 + 2; ++l) {
      const int g = wid + 4 * l;              // 0..15, 8 rows each
      gload16(Ab + (size_t)(rowBase + g * 8) * 1024 + seg + laneOff, dst + g * 512);
      gload16(Bb + (size_t)(colBase + g * 8) * 1024 + seg + laneOff, dst + 8192 + g * 512);
    }
  };

  STAGE_half(0, 0);
  STAGE_half(0, 1);
  asm volatile("s_waitcnt vmcnt(0)" ::: "memory");
  __builtin_amdgcn_s_barrier();
  __builtin_amdgcn_sched_barrier(0);

  for (int t = 0; t < 24; ++t) {
    const short* As = &ring[t & 1][0];
    const short* Bs = &ring[t & 1][8192];
#pragma unroll
    for (int kh = 0; kh < 2; ++kh) {          // kh ascending -> bit-identical accumulation
      const int ch = ((kh * 4 + q) ^ (c & 7)) * 8;   // deswizzled 16B chunk
      bf16x8 ar[4], br[4];
#pragma unroll
      for (int rf = 0; rf < 4; ++rf)
        ar[rf] = *reinterpret_cast<const bf16x8*>(&As[(wm * 64 + rf * 16 + c) * 64 + ch]);
#pragma unroll
      for (int cf = 0; cf < 4; ++cf)
        br[cf] = *reinterpret_cast<const bf16x8*>(&Bs[(wn * 64 + cf * 16 + c) * 64 + ch]);
      if (t + 1 < 24) STAGE_half(t + 1, kh);  // into the other buffer, in flight during MFMA
      __builtin_amdgcn_s_setprio(1);
#pragma unroll
      for (int rf = 0; rf < 4; ++rf)
#pragma unroll
        for (int cf = 0; cf < 4; ++cf)
          acc[rf][cf] = __builtin_amdgcn_mfma_f32_16x16x32_bf16(ar[rf], br[cf], acc[rf][cf], 0, 0, 0);
      __builtin_amdgcn_s_setprio(0);
      __builtin_amdgcn_sched_barrier(0);      // sub-phase boundary: frags die here
    }
    if (t + 1 < 24) {
      asm volatile("s_waitcnt vmcnt(0)" ::: "memory");
      __builtin_amdgcn_s_barrier();
      __builtin_amdgcn_sched_barrier(0);
    }
  }

  // epilogue inputs loaded here (not hoisted across the K-loop)
  float4 R4[4];
  float cq[4];
#pragma unroll
  for (int rf = 0; rf < 4; ++rf)
    R4[rf] = *reinterpret_cast<const float4*>(&Rrow[rowBase + wm * 64 + rf * 16 + q * 4]);
#pragma unroll
  for (int cf = 0; cf < 4; ++cf)
    cq[cf] = cbsq[colBase + wn * 64 + cf * 16 + c];

  // epilogue: d~ -> per-wave top-3 over 64 cols (validated math)
#pragma unroll
  for (int rf = 0; rf < 4; ++rf) {
#pragma unroll
    for (int jj = 0; jj < 4; ++jj) {
      const float Rv = (jj == 0) ? R4[rf].x : (jj == 1) ? R4[rf].y : (jj == 2) ? R4[rf].z : R4[rf].w;
      unsigned int v[4];
#pragma unroll
      for (int cf = 0; cf < 4; ++cf) {
        float d = __fadd_rn(__fsub_rn(Rv, __fmul_rn(2.0f, acc[rf][cf][jj])), cq[cf]);
        d = fmaxf(d, 0.0f);
        v[cf] = (__float_as_uint(d) & 0xFFFFFF80u) | (unsigned int)(wn * 64 + cf * 16 + c);
      }
      const unsigned int m01 = min(v[0], v[1]), M01 = max(v[0], v[1]);
      const unsigned int m23 = min(v[2], v[3]), M23 = max(v[2], v[3]);
      unsigned int s0 = min(m01, m23);
      const unsigned int x = max(m01, m23), mM = min(M01, M23);
      unsigned int s1 = min(x, mM);
      unsigned int s2 = min(max(x, mM), max(M01, M23));
#pragma unroll
      for (int m = 1; m < 16; m <<= 1) {
        const unsigned int t0 = (unsigned int)__shfl_xor((int)s0, m);
        const unsigned int t1 = (unsigned int)__shfl_xor((int)s1, m);
        const unsigned int t2 = (unsigned int)__shfl_xor((int)s2, m);
        const unsigned int bb = max(s0, t0), aa = min(s1, t1);
        const unsigned int r0 = min(s0, t0);
        const unsigned int r1 = min(bb, aa);
        const unsigned int r2 = min(max(bb, aa), min(s2, t2));
        s0 = r0; s1 = r1; s2 = r2;
      }
      if (c == 0) {
        const int lrow = rf * 16 + q * 4 + jj;      // 0..63 within wave
        trip[wid][lrow][0] = s0;
        trip[wid][lrow][1] = s1;
        trip[wid][lrow][2] = s2;
      }
    }
  }
  __syncthreads();
  // wave-pair merge (wn 0/1 share rows): even wid writes the 128-col triple
  if ((wid & 1) == 0) {
    const unsigned int a0 = trip[wid][lane][0], a1 = trip[wid][lane][1], a2 = trip[wid][lane][2];
    const unsigned int b0 = trip[wid + 1][lane][0], b1 = trip[wid + 1][lane][1], b2 = trip[wid + 1][lane][2];
    const unsigned int bb = max(a0, b0), aa = min(a1, b1);
    const unsigned int s0 = min(a0, b0);
    const unsigned int s1 = min(bb, aa);
    const unsigned int s2 = min(max(bb, aa), min(a2, b2));
    const int row = rowBase + (wid >> 1) * 64 + lane;
    unsigned int* kp = keys + (size_t)row * 24 + cbk * 3;
    kp[0] = s0; kp[1] = s1; kp[2] = s2;
  }
}

// ---------------------------------------------------------------------------
// Fused per-level finish: winner (reduce + exact guarded rescore, validated)
// -> codes, residual subtract (exact), next-level splits (SWIZZLED like prep),
// numpy-tree row norm, usage bincount.  One wave per row.
// do_write=0 at the last level skips the 64MB residual store (finalize_zq
// overwrites zq anyway); R/chain still computed for closs.
// ---------------------------------------------------------------------------
__global__ __launch_bounds__(256) void level_finish_kernel(
    const unsigned int* __restrict__ keys, const float* rin, float* rout,
    const float* __restrict__ cb, const float* __restrict__ cbsq,
    float* __restrict__ Rrow, float* __restrict__ usage,
    float* __restrict__ codes, unsigned short* __restrict__ Ahi,
    unsigned short* __restrict__ Alo, int level, int do_split, int do_write) {
  __shared__ float buf[4][DDIM];
  const int wid  = threadIdx.x >> 6;
  const int lane = threadIdx.x & 63;
  const int row  = blockIdx.x * 4 + wid;

  // ---- winner ----
  const unsigned int k = (lane < 24) ? keys[(size_t)row * 24 + lane] : 0xFFFFFFFFu;
  const int mycode = (lane < 24) ? ((lane / 3) * 128 + (int)(k & 127u)) : 0x7FFFFFFF;
  const float Rv_old = Rrow[row];
  unsigned int g = k;
#pragma unroll
  for (int m = 1; m < 64; m <<= 1) g = min(g, (unsigned int)__shfl_xor((int)g, m));
  const float dmin = __uint_as_float(g & 0xFFFFFF80u);
  const float W = 0.010f + 5.0e-4f * sqrtf(Rv_old);
  const bool cand = (lane < 24) && (__uint_as_float(k & 0xFFFFFF80u) <= dmin + W);
  const unsigned long long mask = __ballot(cand);
  int winner;
  if (__popcll(mask) == 1) {
    int w = cand ? mycode : 0x7FFFFFFF;
#pragma unroll
    for (int m = 1; m < 64; m <<= 1) w = min(w, __shfl_xor(w, m));
    winner = w;
  } else {
    float db = __builtin_inff();
    int   ib = 0x7FFFFFFF;
    if (cand) {
      const float4* rr = reinterpret_cast<const float4*>(rin + (size_t)row * DDIM);
      const float4* cc = reinterpret_cast<const float4*>(cb + (size_t)mycode * DDIM);
      float pp = 0.0f;
      for (int t = 0; t < DDIM / 4; ++t) {   // exact ascending fmaf chain (BLAS order)
        const float4 a = rr[t], b = cc[t];
        pp = fmaf(a.x, b.x, pp); pp = fmaf(a.y, b.y, pp);
        pp = fmaf(a.z, b.z, pp); pp = fmaf(a.w, b.w, pp);
      }
      db = __fadd_rn(__fsub_rn(Rv_old, __fmul_rn(2.0f, pp)), cbsq[mycode]);
      ib = mycode;
    }
#pragma unroll
    for (int m = 1; m < 64; m <<= 1) {
      const float od = __shfl_xor(db, m);
      const int   oi = __shfl_xor(ib, m);
      if (od < db || (od == db && oi < ib)) { db = od; ib = oi; }
    }
    winner = ib;
  }

  // ---- subtract + split + rowsq ----
  const float4* r4 = reinterpret_cast<const float4*>(rin + (size_t)row * DDIM) + lane * 2;
  const float4* q4 = reinterpret_cast<const float4*>(cb + (size_t)winner * DDIM) + lane * 2;
  float4* o4 = reinterpret_cast<float4*>(rout + (size_t)row * DDIM) + lane * 2;
  float vals[8];
#pragma unroll
  for (int t = 0; t < 2; ++t) {
    float4 r = r4[t], qv = q4[t], o;
    o.x = __fsub_rn(r.x, qv.x);
    o.y = __fsub_rn(r.y, qv.y);
    o.z = __fsub_rn(r.z, qv.z);
    o.w = __fsub_rn(r.w, qv.w);
    if (do_write) o4[t] = o;
    *reinterpret_cast<float4*>(&buf[wid][lane * 8 + t * 4]) = o;
    vals[t * 4 + 0] = o.x; vals[t * 4 + 1] = o.y;
    vals[t * 4 + 2] = o.z; vals[t * 4 + 3] = o.w;
  }
  if (do_split) {
    u16x8 hh, ll;
#pragma unroll
    for (int e = 0; e < 8; ++e) {
      const unsigned short h = bf16_rn(vals[e]);
      hh[e] = h;
      ll[e] = bf16_rn(__fsub_rn(vals[e], bf16_f(h)));
    }
    const int pos = (lane & 56) | ((lane & 7) ^ (row & 7));  // chunk swizzle (match prep)
    *reinterpret_cast<u16x8*>(&Ahi[(size_t)row * DDIM + pos * 8]) = hh;
    *reinterpret_cast<u16x8*>(&Alo[(size_t)row * DDIM + pos * 8]) = ll;
  }
  float chain = 0.0f;
  if (lane < 32) {
    const int base = (lane >> 3) * 128 + (lane & 7);
    float a = buf[wid][base];
    chain = __fmul_rn(a, a);
#pragma unroll
    for (int t = 1; t < 16; ++t) {
      a = buf[wid][base + 8 * t];
      chain = __fadd_rn(chain, __fmul_rn(a, a));
    }
  }
  chain = __fadd_rn(chain, __shfl_xor(chain, 1));
  chain = __fadd_rn(chain, __shfl_xor(chain, 2));
  chain = __fadd_rn(chain, __shfl_xor(chain, 4));
  chain = __fadd_rn(chain, __shfl_xor(chain, 8));
  chain = __fadd_rn(chain, __shfl_xor(chain, 16));
  if (lane == 0) {
    Rrow[row] = chain;
    atomicAdd(&usage[winner], 1.0f);
    codes[(size_t)row * LEVELS + level] = (float)winner;
  }
}

// ---------------------------------------------------------------------------
// Fallback VALU argmin (round-3 path, bit-exact-validated) for small ws.
// ---------------------------------------------------------------------------
#define BM 64
#define BN 256
#define DT 32
#define LDP (DT + 4)

__global__ __launch_bounds__(256) void argmin_kernel(const float* __restrict__ res,
                                                     const float* __restrict__ cb,
                                                     const float* __restrict__ Rr_,
                                                     const float* __restrict__ cbsq,
                                                     float* __restrict__ codes,
                                                     int level) {
  __shared__ float As_[BM][LDP];
  __shared__ float Bs_[BN][LDP];
  const int tid = threadIdx.x;
  const int tx = tid & 15;
  const int ty = tid >> 4;
  const size_t brow = (size_t)blockIdx.x * BM;
  float minv[4]; int mini[4]; float Rv[4];
#pragma unroll
  for (int i = 0; i < 4; ++i) { minv[i] = __builtin_inff(); mini[i] = 0; Rv[i] = Rr_[brow + ty + 16 * i]; }
  for (int nc = 0; nc < KCODES; nc += BN) {
    float acc[4][16];
#pragma unroll
    for (int i = 0; i < 4; ++i)
#pragma unroll
      for (int j = 0; j < 16; ++j) acc[i][j] = 0.0f;
    for (int dt = 0; dt < DDIM; dt += DT) {
      __syncthreads();
#pragma unroll
      for (int qq = 0; qq < 2; ++qq) {
        const int ff = tid + qq * 256; const int r = ff >> 3; const int seg = (ff & 7) * 4;
        *reinterpret_cast<float4*>(&As_[r][seg]) =
            *reinterpret_cast<const float4*>(&res[(brow + r) * DDIM + dt + seg]);
      }
#pragma unroll
      for (int qq = 0; qq < 8; ++qq) {
        const int ff = tid + qq * 256; const int r = ff >> 3; const int seg = (ff & 7) * 4;
        *reinterpret_cast<float4*>(&Bs_[r][seg]) =
            *reinterpret_cast<const float4*>(&cb[(size_t)(nc + r) * DDIM + dt + seg]);
      }
      __syncthreads();
#pragma unroll
      for (int dd = 0; dd < DT; dd += 4) {
        float4 av[4];
#pragma unroll
        for (int i = 0; i < 4; ++i) av[i] = *reinterpret_cast<const float4*>(&As_[ty + 16 * i][dd]);
#pragma unroll
        for (int j = 0; j < 16; ++j) {
          const float4 bv = *reinterpret_cast<const float4*>(&Bs_[tx + 16 * j][dd]);
#pragma unroll
          for (int i = 0; i < 4; ++i) {
            acc[i][j] = fmaf(av[i].x, bv.x, acc[i][j]);
            acc[i][j] = fmaf(av[i].y, bv.y, acc[i][j]);
            acc[i][j] = fmaf(av[i].z, bv.z, acc[i][j]);
            acc[i][j] = fmaf(av[i].w, bv.w, acc[i][j]);
          }
        }
      }
    }
#pragma unroll
    for (int j = 0; j < 16; ++j) {
      const int code = nc + tx + 16 * j;
      const float cq = cbsq[code];
#pragma unroll
      for (int i = 0; i < 4; ++i) {
        const float dist = __fadd_rn(__fsub_rn(Rv[i], __fmul_rn(2.0f, acc[i][j])), cq);
        if (dist < minv[i]) { minv[i] = dist; mini[i] = code; }
      }
    }
  }
#pragma unroll
  for (int m = 1; m < 16; m <<= 1) {
#pragma unroll
    for (int i = 0; i < 4; ++i) {
      const float ov = __shfl_xor(minv[i], m);
      const int   oi = __shfl_xor(mini[i], m);
      if (ov < minv[i] || (ov == minv[i] && oi < mini[i])) { minv[i] = ov; mini[i] = oi; }
    }
  }
  if (tx == 0) {
#pragma unroll
    for (int i = 0; i < 4; ++i)
      codes[(brow + ty + 16 * i) * LEVELS + level] = (float)mini[i];
  }
}

// fallback per-level tail (validated)
__global__ __launch_bounds__(256) void sub_split_rowsq_kernel(
    const float* rin, float* rout, const float* __restrict__ cb,
    const float* __restrict__ codes, float* __restrict__ usage,
    float* __restrict__ Rout, int level) {
  __shared__ float buf[4][DDIM];
  const int wid  = threadIdx.x >> 6;
  const int lane = threadIdx.x & 63;
  const int row  = blockIdx.x * 4 + wid;
  const int idx = (int)codes[(size_t)row * LEVELS + level];
  const float4* r4 = reinterpret_cast<const float4*>(rin + (size_t)row * DDIM) + lane * 2;
  const float4* q4 = reinterpret_cast<const float4*>(cb + (size_t)idx * DDIM) + lane * 2;
  float4* o4 = reinterpret_cast<float4*>(rout + (size_t)row * DDIM) + lane * 2;
#pragma unroll
  for (int t = 0; t < 2; ++t) {
    float4 r = r4[t], q = q4[t], o;
    o.x = __fsub_rn(r.x, q.x);
    o.y = __fsub_rn(r.y, q.y);
    o.z = __fsub_rn(r.z, q.z);
    o.w = __fsub_rn(r.w, q.w);
    o4[t] = o;
    *reinterpret_cast<float4*>(&buf[wid][lane * 8 + t * 4]) = o;
  }
  float chain = 0.0f;
  if (lane < 32) {
    const int base = (lane >> 3) * 128 + (lane & 7);
    float a = buf[wid][base];
    chain = __fmul_rn(a, a);
#pragma unroll
    for (int t = 1; t < 16; ++t) {
      a = buf[wid][base + 8 * t];
      chain = __fadd_rn(chain, __fmul_rn(a, a));
    }
  }
  chain = __fadd_rn(chain, __shfl_xor(chain, 1));
  chain = __fadd_rn(chain, __shfl_xor(chain, 2));
  chain = __fadd_rn(chain, __shfl_xor(chain, 4));
  chain = __fadd_rn(chain, __shfl_xor(chain, 8));
  chain = __fadd_rn(chain, __shfl_xor(chain, 16));
  if (lane == 0) {
    Rout[row] = chain;
    atomicAdd(&usage[idx], 1.0f);
  }
}

__global__ __launch_bounds__(256) void sumR_kernel(const float* __restrict__ R,
                                                   float* __restrict__ slot) {
  const int t = blockIdx.x * 256 + threadIdx.x;
  float s = 0.0f;
#pragma unroll
  for (int k = 0; k < 4; ++k) s += R[t + k * 8192];
#pragma unroll
  for (int m = 1; m < 64; m <<= 1) s += __shfl_xor(s, m);
  __shared__ float ws[4];
  if ((threadIdx.x & 63) == 0) ws[threadIdx.x >> 6] = s;
  __syncthreads();
  if (threadIdx.x == 0) atomicAdd(slot, ((ws[0] + ws[1]) + (ws[2] + ws[3])));
}

__global__ __launch_bounds__(256) void finalize_zq_kernel(const float* __restrict__ z,
                                                          const float* __restrict__ cb,
                                                          const float* __restrict__ codes,
                                                          float* __restrict__ zq) {
  const int row  = (int)((blockIdx.x * 256 + threadIdx.x) >> 6);
  const int lane = threadIdx.x & 63;
  int c[4];
#pragma unroll
  for (int l = 0; l < 4; ++l) c[l] = (int)codes[(size_t)row * LEVELS + l];
#pragma unroll
  for (int t = 0; t < 2; ++t) {
    const int o = lane * 8 + t * 4;
    float4 s = *reinterpret_cast<const float4*>(&cb[(size_t)c[0] * DDIM + o]);
#pragma unroll
    for (int l = 1; l < 4; ++l) {
      const float4 q = *reinterpret_cast<const float4*>(&cb[(size_t)c[l] * DDIM + o]);
      s.x = __fadd_rn(s.x, q.x);
      s.y = __fadd_rn(s.y, q.y);
      s.z = __fadd_rn(s.z, q.z);
      s.w = __fadd_rn(s.w, q.w);
    }
    const float4 zz = *reinterpret_cast<const float4*>(&z[(size_t)row * DDIM + o]);
    float4 r;
    r.x = __fadd_rn(zz.x, __fsub_rn(s.x, zz.x));
    r.y = __fadd_rn(zz.y, __fsub_rn(s.y, zz.y));
    r.z = __fadd_rn(zz.z, __fsub_rn(s.z, zz.z));
    r.w = __fadd_rn(zz.w, __fsub_rn(s.w, zz.w));
    *reinterpret_cast<float4*>(&zq[(size_t)row * DDIM + o]) = r;
  }
}

__global__ void closs_final_kernel(const float* __restrict__ acc, float* __restrict__ out) {
  if (threadIdx.x == 0 && blockIdx.x == 0) {
    float c = 0.0f;
#pragma unroll
    for (int l = 0; l < 4; ++l)
      c = __fadd_rn(c, __fmul_rn(acc[l], 0x1p-24f));
    out[0] = c;
  }
}

extern "C" void kernel_launch(void* const* d_in, const int* in_sizes, int n_in,
                              void* d_out, int out_size, void* d_ws, size_t ws_size,
                              hipStream_t stream) {
  const float* z  = (const float*)d_in[0];
  const float* cb = (const float*)d_in[1];
  float* out   = (float*)d_out;
  float* zq    = out;
  float* closs = out + CLOSS_OFF;
  float* codes = out + CODES_OFF;
  float* usage = out + USAGE_OFF;

  float* R    = (float*)d_ws;
  float* cbsq = R + NROWS;
  float* cacc = cbsq + KCODES;

  const size_t WS_NEED = (size_t)(NROWS + KCODES + 4) * 4       // R, cbsq, cacc
                       + (size_t)NROWS * 24 * 4                  // keys
                       + 2ull * KCODES * DDIM * 2                // B splits
                       + 2ull * NROWS * DDIM * 2;                // A splits

  hipMemsetAsync(usage, 0, KCODES * sizeof(float), stream);
  hipMemsetAsync(cacc, 0, LEVELS * sizeof(float), stream);

  if (ws_size >= WS_NEED) {
    unsigned int*   keys = (unsigned int*)(cacc + 4);
    unsigned short* Bhi  = (unsigned short*)(keys + (size_t)NROWS * 24);
    unsigned short* Blo  = Bhi + (size_t)KCODES * DDIM;
    unsigned short* Ahi  = Blo + (size_t)KCODES * DDIM;
    unsigned short* Alo  = Ahi + (size_t)NROWS * DDIM;

    prep_kernel<<<NROWS / 4, 256, 0, stream>>>(z, R, Ahi, Alo, NROWS);
    prep_kernel<<<KCODES / 4, 256, 0, stream>>>(cb, cbsq, Bhi, Blo, KCODES);

    for (int l = 0; l < LEVELS; ++l) {
      const float* res = (l == 0) ? z : zq;
      gemm_topk_kernel<<<2048, 256, 0, stream>>>(Ahi, Alo, Bhi, Blo, R, cbsq, keys);
      level_finish_kernel<<<NROWS / 4, 256, 0, stream>>>(keys, res, zq, cb, cbsq, R,
                                                         usage, codes, Ahi, Alo, l,
                                                         (l < 3) ? 1 : 0,
                                                         (l < 3) ? 1 : 0);
      sumR_kernel<<<32, 256, 0, stream>>>(R, cacc + l);
    }
  } else {
    prep_kernel<<<NROWS / 4, 256, 0, stream>>>(z, R, (unsigned short*)(cacc + 4),
                                               (unsigned short*)(cacc + 4) + NROWS, NROWS);
    prep_kernel<<<KCODES / 4, 256, 0, stream>>>(cb, cbsq, (unsigned short*)(cacc + 4),
                                                (unsigned short*)(cacc + 4) + KCODES, KCODES);
    for (int l = 0; l < LEVELS; ++l) {
      const float* res = (l == 0) ? z : zq;
      argmin_kernel<<<NROWS / BM, 256, 0, stream>>>(res, cb, R, cbsq, codes, l);
      sub_split_rowsq_kernel<<<NROWS / 4, 256, 0, stream>>>(res, zq, cb, codes, usage, R, l);
      sumR_kernel<<<32, 256, 0, stream>>>(R, cacc + l);
    }
  }

  finalize_zq_kernel<<<NROWS / 4, 256, 0, stream>>>(z, cb, codes, zq);
  closs_final_kernel<<<1, 64, 0, stream>>>(cacc, closs);
}